// Round 5
// baseline (1932.296 us; speedup 1.0000x reference)
//
#include <hip/hip_runtime.h>
#include <hip/hip_bf16.h>
#include <hip/hip_fp16.h>

#define Bn 8
#define Hn 128
#define Wn 128
#define Cn 192
#define Gn 6
#define GCn 32
#define NPIX (Bn*Hn*Wn)   // 131072

typedef __attribute__((ext_vector_type(8))) short v8s;
typedef __attribute__((ext_vector_type(4))) float v4f;
typedef __attribute__((ext_vector_type(2))) float v2f;
typedef __hip_bfloat16 bf16;

__device__ __forceinline__ float b2f(bf16 v){ return __bfloat162float(v); }
// bf16 pair (lo,hi) -> float2 ; consumed by v_pk_fma_f32
__device__ __forceinline__ v2f up2(unsigned u){
    return (v2f){ __uint_as_float(u << 16), __uint_as_float(u & 0xffff0000u) };
}

// ---------------- fp32 -> bf16 conversion (8 elems/thread) ----------------
__global__ __launch_bounds__(256) void cvt_bf16(const float* __restrict__ in,
                                                bf16* __restrict__ out, long n)
{
    long base = ((long)blockIdx.x*256 + threadIdx.x)*8;
    if (base >= n) return;
    float v[8];
    *(float4*)(v)   = *(const float4*)(in + base);
    *(float4*)(v+4) = *(const float4*)(in + base + 4);
    bf16 o[8];
    #pragma unroll
    for (int j=0;j<8;j++) o[j] = __float2bfloat16(v[j]);
    *(uint4*)(out + base) = *(uint4*)o;
}

// ---------------- weight swizzle (fp32 in) into MFMA B-fragment order ----------------
// frag[nt(12)][ks(6)][lane(64)][j(8)]  element = W[k][n]
//   k = ks*32 + (lane>>4)*8 + j ,  n = nt*16 + (lane&15) ; n>=N -> 0
__global__ __launch_bounds__(256) void swizzle_w(const float* __restrict__ w,
                                                 bf16* __restrict__ out, int N)
{
    int idx = blockIdx.x*256 + threadIdx.x;        // < 36864
    int j = idx & 7, lane = (idx>>3)&63, ks = (idx>>9)%6, nt = idx/3072;
    int k = ks*32 + ((lane>>4)<<3) + j;
    int n = (nt<<4) + (lane&15);
    out[idx] = (n < N) ? __float2bfloat16(w[k*N + n]) : __float2bfloat16(0.0f);
}

// Combined weight: Wcombo[k][m] = sum_n w_pw[k][n] * Wcat[n][m], Wcat = [w_off | w_mask]
// bcombo[m] = sum_n b_pw[n]*Wcat[n][m] + bcat[m]. Eliminates the pointwise GEMM entirely.
// split-K x8 (8 threads/output, 24-elem partials, shfl_xor reduce) - round-4 measured-good.
__global__ __launch_bounds__(256) void swizzle_omc(const float* __restrict__ wpw,
        const float* __restrict__ woff, const float* __restrict__ wmask,
        const float* __restrict__ bpw, const float* __restrict__ boff,
        const float* __restrict__ bmask, bf16* __restrict__ out, float* __restrict__ biascat)
{
    int gid = blockIdx.x*256 + threadIdx.x;
    int s = gid & 7; int n0 = s*24;
    if (gid < 36864*8) {
        int idx = gid >> 3;
        int j = idx & 7, lane = (idx>>3)&63, ks = (idx>>9)%6, nt = idx/3072;
        int k = ks*32 + ((lane>>4)<<3) + j;
        int m = (nt<<4) + (lane&15);
        float acc = 0.0f;
        if (m < 108) {
            const float* wr = wpw + k*192 + n0;
            const float* wc = woff + (size_t)n0*108 + m;
            #pragma unroll 6
            for (int i=0;i<24;i++) acc += wr[i] * wc[(size_t)i*108];
        } else if (m < 162) {
            const float* wr = wpw + k*192 + n0;
            const float* wc = wmask + (size_t)n0*54 + (m-108);
            #pragma unroll 6
            for (int i=0;i<24;i++) acc += wr[i] * wc[(size_t)i*54];
        }
        acc += __shfl_xor(acc, 1);
        acc += __shfl_xor(acc, 2);
        acc += __shfl_xor(acc, 4);
        if (s == 0) out[idx] = __float2bfloat16(acc);
    } else {
        int t = gid - 36864*8;            // < 1536
        int idx = t >> 3;                 // 0..191
        float bv = 0.0f;
        if (idx < 108) {
            #pragma unroll 6
            for (int i=0;i<24;i++) bv += bpw[n0+i] * woff[(size_t)(n0+i)*108 + idx];
        } else if (idx < 162) {
            #pragma unroll 6
            for (int i=0;i<24;i++) bv += bpw[n0+i] * wmask[(size_t)(n0+i)*54 + (idx-108)];
        }
        bv += __shfl_xor(bv, 1);
        bv += __shfl_xor(bv, 2);
        bv += __shfl_xor(bv, 4);
        if (s == 0) {
            float base = 0.0f;
            if (idx < 108) base = boff[idx];
            else if (idx < 162) base = bmask[idx-108];
            biascat[idx] = bv + base;
        }
    }
}

// ---------------- MFMA GEMM, B fully in registers: [131072 x 192] @ [192 x <=192] ----------------
// Flat grid of 1024 blocks. XCD chunk swizzle (measured-good round 1). Output type
// templated: bf16 / fp16 / fp32 (fp16 outputs feed deform_sample's v_fma_mix path).
__device__ __forceinline__ void store_out(bf16* p, float v){ *p = __float2bfloat16(v); }
__device__ __forceinline__ void store_out(float* p, float v){ *p = v; }
__device__ __forceinline__ void store_out(__half* p, float v){ *p = __float2half(v); }

template<typename OutT>
__global__ __launch_bounds__(256, 2) void gemm6r(const bf16* __restrict__ A,
        const v8s* __restrict__ wfrag, const float* __restrict__ bias,
        OutT* __restrict__ Cmat, int Nreal, int Nstride)
{
    int tid = threadIdx.x;
    int wave = tid >> 6, lane = tid & 63;
    int q = lane >> 4, r = lane & 15;
    int n = blockIdx.x;                 // 1024 blocks
    int l = (n & 7) * 128 + (n >> 3);   // XCD chunk swizzle (bijective, 1024=8*128)
    int yhalf = l & 1;                  // col-half; pair (l, l^1) shares A rows
    int mt0 = l >> 1;                   // [0,512)
    const v8s* wsrc = wfrag + yhalf*(36*64) + lane;
    v8s breg[36];
    #pragma unroll
    for (int f=0; f<36; f++) breg[f] = wsrc[f*64];
    int col0 = yhalf*96;
    float bv[6];
    #pragma unroll
    for (int nt=0; nt<6; nt++) {
        int col = col0 + nt*16 + r;
        bv[nt] = (col < Nreal) ? bias[col] : 0.0f;
    }
    const int MT = NPIX/64;   // 2048
    for (int mt = mt0; mt < MT; mt += 512) {
        const bf16* Ap = A + (size_t)(mt*64 + wave*16 + r)*Cn + q*8;
        v8s av[6];
        #pragma unroll
        for (int ks=0; ks<6; ks++) av[ks] = *(const v8s*)(Ap + ks*32);
        v4f acc[6];
        #pragma unroll
        for (int nt=0;nt<6;nt++) acc[nt] = (v4f){0.f,0.f,0.f,0.f};
        #pragma unroll
        for (int ks=0; ks<6; ks++)
            #pragma unroll
            for (int nt=0;nt<6;nt++)
                acc[nt] = __builtin_amdgcn_mfma_f32_16x16x32_bf16(
                              av[ks], breg[nt*6+ks], acc[nt], 0, 0, 0);
        int orow = mt*64 + wave*16 + q*4;
        #pragma unroll
        for (int nt=0;nt<6;nt++) {
            int col = col0 + nt*16 + r;
            if (col < Nreal) {
                #pragma unroll
                for (int i=0;i<4;i++)
                    store_out(&Cmat[(size_t)(orow+i)*Nstride + col], acc[nt][i] + bv[nt]);
            }
        }
    }
}

// ---------------- depthwise 3x3 + bias + SiLU, 16 ch/thread, packed-f32 acc ----------------
// EXACT round-1/round-3 measured version (round-4 prefetch variant was an unattributed
// ~+25us regression: 36 live loads at launch_bounds(256,2) halved occupancy). XCD chunk
// swizzle: 6144 = 8*768; each XCD owns one image.
__global__ __launch_bounds__(256, 4) void dw_silu(const bf16* __restrict__ x,
        const bf16* __restrict__ wdwb, const float* __restrict__ bdw, bf16* __restrict__ out)
{
    int bid = blockIdx.x;
    int bsw = (bid & 7) * 768 + (bid >> 3);      // bijective, 6144 = 8*768
    int idx = bsw*256 + threadIdx.x;             // NPIX*12 threads, 16 ch each
    int c16 = idx % 12; int pix = idx / 12;
    int b = pix >> 14; int hw = pix & 16383; int h = hw >> 7, w = hw & 127;
    int cb = c16*16;
    v2f acc2[8];
    #pragma unroll
    for (int j=0;j<8;j++) acc2[j] = (v2f){bdw[cb+2*j], bdw[cb+2*j+1]};
    #pragma unroll
    for (int dy=-1;dy<=1;dy++){
        int hh=h+dy; if ((unsigned)hh >= (unsigned)Hn) continue;
        #pragma unroll
        for (int dx=-1;dx<=1;dx++){
            int ww=w+dx; if ((unsigned)ww >= (unsigned)Wn) continue;
            const uint4* xp = (const uint4*)(x + ((size_t)((b<<14)+(hh<<7)+ww))*Cn + cb);
            const uint4* wp = (const uint4*)(wdwb + ((dy+1)*3+(dx+1))*Cn + cb);
            #pragma unroll
            for (int cs=0;cs<2;cs++){
                uint4 xu = xp[cs], wu = wp[cs];
                unsigned xa[4] = {xu.x,xu.y,xu.z,xu.w};
                unsigned wa[4] = {wu.x,wu.y,wu.z,wu.w};
                #pragma unroll
                for (int t=0;t<4;t++)
                    acc2[cs*4+t] += up2(xa[t]) * up2(wa[t]);
            }
        }
    }
    bf16 ov[16];
    #pragma unroll
    for (int j=0;j<8;j++){
        float v0 = acc2[j].x, v1 = acc2[j].y;
        ov[2*j]   = __float2bfloat16(v0 / (1.f + __expf(-v0)));
        ov[2*j+1] = __float2bfloat16(v1 / (1.f + __expf(-v1)));
    }
    uint4* op = (uint4*)(out + (size_t)pix*Cn + cb);
    op[0] = ((uint4*)ov)[0];
    op[1] = ((uint4*)ov)[1];
}

// ---------------- deformable sampling, 2 threads per (pix,group), 16 ch each ----------------
// v3: P and OM in fp16. Accumulate via fmaf(__half2float(h), w, acc) -> v_fma_mix_f32
// (2 VALU/u32 vs bf16's shift+and+pk_fma 3/u32). 32-bit uint4-granule indices from a
// uniform SGPR base (saddr loads; +16B/+384B fold to imm offsets). XCD chunk swizzle +
// 2-ahead register pipeline unchanged from the round-1 measured structure.

#define LOADTAP(K, S)                                                        \
  { __half2 o2 = *(const __half2*)&op[K];                                    \
    float ph = fmaf(__half2float(o2.x), 0.1f, (float)(h + (K)/3 - 1));       \
    float pw = fmaf(__half2float(o2.y), 0.1f, (float)(w + (K)%3 - 1));       \
    ph = fminf(fmaxf(ph, 0.f), 127.f);                                       \
    pw = fminf(fmaxf(pw, 0.f), 127.f);                                       \
    int hf = (int)ph, wf = (int)pw;                                          \
    fh##S = ph - (float)hf; fw##S = pw - (float)wf;                          \
    int a00 = qbase + hf*3072 + wf*24;                                       \
    int dh  = (hf < 127) ? 3072 : 0;                                         \
    int dwq = (wf < 127) ? 24 : 0;                                           \
    int a10 = a00 + dh;                                                      \
    S##00[0]=P4[a00];      S##00[1]=P4[a00+1];                               \
    S##01[0]=P4[a00+dwq];  S##01[1]=P4[a00+dwq+1];                           \
    S##10[0]=P4[a10];      S##10[1]=P4[a10+1];                               \
    S##11[0]=P4[a10+dwq];  S##11[1]=P4[a10+dwq+1]; }

#define ACCTAP(K, S)                                                         \
  { float a = att[K];                                                        \
    float w00=(1.f-fh##S)*(1.f-fw##S)*a, w01=(1.f-fh##S)*fw##S*a,            \
          w10=fh##S*(1.f-fw##S)*a, w11=fh##S*fw##S*a;                        \
    _Pragma("unroll")                                                        \
    for (int cs=0;cs<2;cs++){                                                \
      const __half2* x00=(const __half2*)&S##00[cs];                         \
      const __half2* x01=(const __half2*)&S##01[cs];                         \
      const __half2* x10=(const __half2*)&S##10[cs];                         \
      const __half2* x11=(const __half2*)&S##11[cs];                         \
      _Pragma("unroll")                                                      \
      for (int t=0;t<4;t++){                                                 \
        int e0 = cs*8 + 2*t, e1 = e0 + 1;                                    \
        acc[e0] = fmaf(__half2float(x00[t].x), w00, acc[e0]);                \
        acc[e0] = fmaf(__half2float(x01[t].x), w01, acc[e0]);                \
        acc[e0] = fmaf(__half2float(x10[t].x), w10, acc[e0]);                \
        acc[e0] = fmaf(__half2float(x11[t].x), w11, acc[e0]);                \
        acc[e1] = fmaf(__half2float(x00[t].y), w00, acc[e1]);                \
        acc[e1] = fmaf(__half2float(x01[t].y), w01, acc[e1]);                \
        acc[e1] = fmaf(__half2float(x10[t].y), w10, acc[e1]);                \
        acc[e1] = fmaf(__half2float(x11[t].y), w11, acc[e1]);                \
      } } }

__global__ __launch_bounds__(256, 4) void deform_sample(const __half* __restrict__ P,
        const __half* __restrict__ OM, bf16* __restrict__ S)
{
    int bid = blockIdx.x;
    int bsw = (bid & 7) * 768 + (bid >> 3);      // bijective, 6144 = 8*768
    int idx = bsw*256 + threadIdx.x;             // NPIX*12 threads
    int hlf = idx & 1;
    int g = (idx >> 1) % 6;
    int pix = idx / 12;
    int b = pix >> 14; int hw = pix & 16383; int h = hw >> 7, w = hw & 127;

    // offsets: u32 pairs (f16 off_h | f16 off_w), 4B-aligned (g*18 f16 = g*36 B)
    const unsigned* OMu = (const unsigned*)OM;
    int omq = pix*81 + g*9;
    unsigned op[9];
    #pragma unroll
    for (int k=0;k<9;k++) op[k] = OMu[omq + k];

    // mask logits (scalar f16 loads; base only 2B-aligned for odd g)
    const __half* oml = OM + (size_t)pix*162 + 108 + g*9;
    float att[9];
    float m = -1e30f;
    #pragma unroll
    for (int k=0;k<9;k++){ att[k] = __half2float(oml[k]); m = fmaxf(m, att[k]); }
    float ssum = 0.f;
    #pragma unroll
    for (int k=0;k<9;k++){ att[k] = __expf(att[k]-m); ssum += att[k]; }
    float inv = 1.f/ssum;
    #pragma unroll
    for (int k=0;k<9;k++) att[k] *= inv;

    const uint4* P4 = (const uint4*)P;           // uniform base; index in 16B units
    int qbase = b*393216 + (g<<2) + (hlf<<1);    // b*16384*24 + (g*32+hlf*16)/8

    float acc[16];
    #pragma unroll
    for (int j=0;j<16;j++) acc[j] = 0.f;

    uint4 A00[2],A01[2],A10[2],A11[2]; float fhA,fwA;
    uint4 B00[2],B01[2],B10[2],B11[2]; float fhB,fwB;

    // 2-ahead pipeline: loads for taps k+1,k+2 in flight while accumulating tap k
    LOADTAP(0, A)
    LOADTAP(1, B)
    ACCTAP(0, A)  LOADTAP(2, A)
    ACCTAP(1, B)  LOADTAP(3, B)
    ACCTAP(2, A)  LOADTAP(4, A)
    ACCTAP(3, B)  LOADTAP(5, B)
    ACCTAP(4, A)  LOADTAP(6, A)
    ACCTAP(5, B)  LOADTAP(7, B)
    ACCTAP(6, A)  LOADTAP(8, A)
    ACCTAP(7, B)
    ACCTAP(8, A)

    bf16 ov[16];
    #pragma unroll
    for (int j=0;j<16;j++) ov[j] = __float2bfloat16(acc[j]);
    int chbase = g*GCn + hlf*16;
    uint4* sp = (uint4*)(S + (size_t)pix*Cn + chbase);
    sp[0] = ((uint4*)ov)[0];
    sp[1] = ((uint4*)ov)[1];
}

extern "C" void kernel_launch(void* const* d_in, const int* in_sizes, int n_in,
                              void* d_out, int out_size, void* d_ws, size_t ws_size,
                              hipStream_t stream)
{
    const float* x      = (const float*)d_in[0];
    const float* w_in   = (const float*)d_in[1];
    const float* b_in   = (const float*)d_in[2];
    const float* w_dw   = (const float*)d_in[3];
    const float* b_dw   = (const float*)d_in[4];
    const float* w_pw   = (const float*)d_in[5];
    const float* b_pw   = (const float*)d_in[6];
    const float* w_off  = (const float*)d_in[7];
    const float* b_off  = (const float*)d_in[8];
    const float* w_mask = (const float*)d_in[9];
    const float* b_mask = (const float*)d_in[10];
    const float* w_out  = (const float*)d_in[11];
    const float* b_out  = (const float*)d_in[12];
    float* out = (float*)d_out;

    char* ws = (char*)d_ws;
    size_t off = 0;
    auto carve = [&](size_t bytes)->char* {
        char* p = ws + off; off += (bytes + 255) & ~(size_t)255; return p; };
    bf16*   XB = (bf16*)carve((size_t)NPIX*Cn*2);    // bf16 x
    __half* P  = (__half*)carve((size_t)NPIX*Cn*2);  // x_proj (fp16)
    bf16*   D  = (bf16*)carve((size_t)NPIX*Cn*2);    // dw out, later reused as sampled S
    __half* OM = (__half*)carve((size_t)NPIX*162*2); // offsets|mask logits (fp16)
    bf16* wfI = (bf16*)carve(36864*2);
    bf16* wfO = (bf16*)carve(36864*2);
    bf16* wfM = (bf16*)carve(36864*2);
    float* bM = (float*)carve(192*4);
    bf16* WDW = (bf16*)carve(1728*2);

    dim3 blk(256);
    cvt_bf16<<<12288, blk, 0, stream>>>(x, XB, (long)NPIX*Cn);
    cvt_bf16<<<1,     blk, 0, stream>>>(w_dw, WDW, 1728);
    swizzle_w<<<144, blk, 0, stream>>>(w_in,  wfI, 192);
    swizzle_w<<<144, blk, 0, stream>>>(w_out, wfO, 192);
    swizzle_omc<<<1158, blk, 0, stream>>>(w_pw, w_off, w_mask, b_pw, b_off, b_mask, wfM, bM);

    gemm6r<__half><<<1024, blk, 0, stream>>>(XB, (const v8s*)wfI, b_in, P, 192, 192);

    dw_silu<<<6144, blk, 0, stream>>>(XB, WDW, b_dw, D);

    gemm6r<__half><<<1024, blk, 0, stream>>>(D, (const v8s*)wfM, bM, OM, 162, 162);

    deform_sample<<<6144, blk, 0, stream>>>(P, OM, D);   // S overwrites D

    gemm6r<float><<<1024, blk, 0, stream>>>(D, (const v8s*)wfO, b_out, out, 192, 192);
}

// Round 6
// 398.380 us; speedup vs baseline: 4.8504x; 4.8504x over previous
//
#include <hip/hip_runtime.h>
#include <hip/hip_bf16.h>

#define Bn 8
#define Hn 128
#define Wn 128
#define Cn 192
#define Gn 6
#define GCn 32
#define NPIX (Bn*Hn*Wn)   // 131072

typedef __attribute__((ext_vector_type(8))) short v8s;
typedef __attribute__((ext_vector_type(4))) float v4f;
typedef __attribute__((ext_vector_type(2))) float v2f;
typedef __hip_bfloat16 bf16;

__device__ __forceinline__ float b2f(bf16 v){ return __bfloat162float(v); }
__device__ __forceinline__ float lo16(unsigned u){ return __uint_as_float(u << 16); }
__device__ __forceinline__ float hi16(unsigned u){ return __uint_as_float(u & 0xffff0000u); }
// bf16 pair (lo,hi) -> float2 ; consumed by v_pk_fma_f32
__device__ __forceinline__ v2f up2(unsigned u){
    return (v2f){ __uint_as_float(u << 16), __uint_as_float(u & 0xffff0000u) };
}

// ---------------- fp32 -> bf16 conversion (8 elems/thread) ----------------
__global__ __launch_bounds__(256) void cvt_bf16(const float* __restrict__ in,
                                                bf16* __restrict__ out, long n)
{
    long base = ((long)blockIdx.x*256 + threadIdx.x)*8;
    if (base >= n) return;
    float v[8];
    *(float4*)(v)   = *(const float4*)(in + base);
    *(float4*)(v+4) = *(const float4*)(in + base + 4);
    bf16 o[8];
    #pragma unroll
    for (int j=0;j<8;j++) o[j] = __float2bfloat16(v[j]);
    *(uint4*)(out + base) = *(uint4*)o;
}

// ---------------- weight swizzle (fp32 in) into MFMA B-fragment order ----------------
// frag[nt(12)][ks(6)][lane(64)][j(8)]  element = W[k][n]
//   k = ks*32 + (lane>>4)*8 + j ,  n = nt*16 + (lane&15) ; n>=N -> 0
__global__ __launch_bounds__(256) void swizzle_w(const float* __restrict__ w,
                                                 bf16* __restrict__ out, int N)
{
    int idx = blockIdx.x*256 + threadIdx.x;        // < 36864
    int j = idx & 7, lane = (idx>>3)&63, ks = (idx>>9)%6, nt = idx/3072;
    int k = ks*32 + ((lane>>4)<<3) + j;
    int n = (nt<<4) + (lane&15);
    out[idx] = (n < N) ? __float2bfloat16(w[k*N + n]) : __float2bfloat16(0.0f);
}

// Combined weight: Wcombo[k][m] = sum_n w_pw[k][n] * Wcat[n][m], Wcat = [w_off | w_mask]
// bcombo[m] = sum_n b_pw[n]*Wcat[n][m] + bcat[m]. Eliminates the pointwise GEMM entirely.
// split-K x8 (8 threads/output, 24-elem partials, shfl_xor reduce) - round-4 measured-good.
__global__ __launch_bounds__(256) void swizzle_omc(const float* __restrict__ wpw,
        const float* __restrict__ woff, const float* __restrict__ wmask,
        const float* __restrict__ bpw, const float* __restrict__ boff,
        const float* __restrict__ bmask, bf16* __restrict__ out, float* __restrict__ biascat)
{
    int gid = blockIdx.x*256 + threadIdx.x;
    int s = gid & 7; int n0 = s*24;
    if (gid < 36864*8) {
        int idx = gid >> 3;
        int j = idx & 7, lane = (idx>>3)&63, ks = (idx>>9)%6, nt = idx/3072;
        int k = ks*32 + ((lane>>4)<<3) + j;
        int m = (nt<<4) + (lane&15);
        float acc = 0.0f;
        if (m < 108) {
            const float* wr = wpw + k*192 + n0;
            const float* wc = woff + (size_t)n0*108 + m;
            #pragma unroll 6
            for (int i=0;i<24;i++) acc += wr[i] * wc[(size_t)i*108];
        } else if (m < 162) {
            const float* wr = wpw + k*192 + n0;
            const float* wc = wmask + (size_t)n0*54 + (m-108);
            #pragma unroll 6
            for (int i=0;i<24;i++) acc += wr[i] * wc[(size_t)i*54];
        }
        acc += __shfl_xor(acc, 1);
        acc += __shfl_xor(acc, 2);
        acc += __shfl_xor(acc, 4);
        if (s == 0) out[idx] = __float2bfloat16(acc);
    } else {
        int t = gid - 36864*8;            // < 1536
        int idx = t >> 3;                 // 0..191
        float bv = 0.0f;
        if (idx < 108) {
            #pragma unroll 6
            for (int i=0;i<24;i++) bv += bpw[n0+i] * woff[(size_t)(n0+i)*108 + idx];
        } else if (idx < 162) {
            #pragma unroll 6
            for (int i=0;i<24;i++) bv += bpw[n0+i] * wmask[(size_t)(n0+i)*54 + (idx-108)];
        }
        bv += __shfl_xor(bv, 1);
        bv += __shfl_xor(bv, 2);
        bv += __shfl_xor(bv, 4);
        if (s == 0) {
            float base = 0.0f;
            if (idx < 108) base = boff[idx];
            else if (idx < 162) base = bmask[idx-108];
            biascat[idx] = bv + base;
        }
    }
}

// ---------------- MFMA GEMM, B fully in registers: [131072 x 192] @ [192 x <=192] ----------------
// Flat grid of 1024 blocks, XCD chunk swizzle (measured-good round 1).
// v2: outer loop is exactly 4 iterations -> fully unrolled with next-iteration A-fragment
// prefetch issued BEFORE the 36-MFMA block, so the ~200-900cy A-load latency hides under
// ~180cy of MFMA plus store issue. VGPR budget: 144 breg + 24 av + 24 nx + 24 acc + addr
// ~= 230 < 256 cap at launch_bounds(256,2) -> no spill, occupancy unchanged.
__device__ __forceinline__ void store_out(bf16* p, float v){ *p = __float2bfloat16(v); }
__device__ __forceinline__ void store_out(float* p, float v){ *p = v; }

template<typename OutT>
__global__ __launch_bounds__(256, 2) void gemm6r(const bf16* __restrict__ A,
        const v8s* __restrict__ wfrag, const float* __restrict__ bias,
        OutT* __restrict__ Cmat, int Nreal, int Nstride)
{
    int tid = threadIdx.x;
    int wave = tid >> 6, lane = tid & 63;
    int q = lane >> 4, r = lane & 15;
    int n = blockIdx.x;                 // 1024 blocks
    int l = (n & 7) * 128 + (n >> 3);   // XCD chunk swizzle (bijective, 1024=8*128)
    int yhalf = l & 1;                  // col-half; pair (l, l^1) shares A rows
    int mt0 = l >> 1;                   // [0,512)
    const v8s* wsrc = wfrag + yhalf*(36*64) + lane;
    v8s breg[36];
    #pragma unroll
    for (int f=0; f<36; f++) breg[f] = wsrc[f*64];
    int col0 = yhalf*96;
    float bv[6];
    #pragma unroll
    for (int nt=0; nt<6; nt++) {
        int col = col0 + nt*16 + r;
        bv[nt] = (col < Nreal) ? bias[col] : 0.0f;
    }
    // A row base for this thread at mt0; each iteration advances 512 row-tiles.
    const bf16* Ap = A + (size_t)(mt0*64 + wave*16 + r)*Cn + q*8;
    const size_t ASTEP = (size_t)512*64*Cn;      // bf16 elems per mt-iteration
    v8s av[6];
    #pragma unroll
    for (int ks=0; ks<6; ks++) av[ks] = *(const v8s*)(Ap + ks*32);
    #pragma unroll
    for (int it=0; it<4; it++) {
        int mt = mt0 + it*512;
        v8s nx[6];
        if (it < 3) {
            const bf16* An = Ap + (size_t)(it+1)*ASTEP;
            #pragma unroll
            for (int ks=0; ks<6; ks++) nx[ks] = *(const v8s*)(An + ks*32);
        }
        v4f acc[6];
        #pragma unroll
        for (int nt=0;nt<6;nt++) acc[nt] = (v4f){0.f,0.f,0.f,0.f};
        #pragma unroll
        for (int ks=0; ks<6; ks++)
            #pragma unroll
            for (int nt=0;nt<6;nt++)
                acc[nt] = __builtin_amdgcn_mfma_f32_16x16x32_bf16(
                              av[ks], breg[nt*6+ks], acc[nt], 0, 0, 0);
        int orow = mt*64 + wave*16 + q*4;
        #pragma unroll
        for (int nt=0;nt<6;nt++) {
            int col = col0 + nt*16 + r;
            if (col < Nreal) {
                #pragma unroll
                for (int i=0;i<4;i++)
                    store_out(&Cmat[(size_t)(orow+i)*Nstride + col], acc[nt][i] + bv[nt]);
            }
        }
        if (it < 3) {
            #pragma unroll
            for (int ks=0; ks<6; ks++) av[ks] = nx[ks];
        }
    }
}

// ---------------- depthwise 3x3 + bias + SiLU, 16 ch/thread, packed-f32 acc ----------------
// EXACT round-1/round-3 measured version. XCD chunk swizzle: 6144 = 8*768; each XCD owns
// one image so the h-1/h/h+1 row reuse of the 3x3 window is served by that XCD's L2.
__global__ __launch_bounds__(256, 4) void dw_silu(const bf16* __restrict__ x,
        const bf16* __restrict__ wdwb, const float* __restrict__ bdw, bf16* __restrict__ out)
{
    int bid = blockIdx.x;
    int bsw = (bid & 7) * 768 + (bid >> 3);      // bijective, 6144 = 8*768
    int idx = bsw*256 + threadIdx.x;             // NPIX*12 threads, 16 ch each
    int c16 = idx % 12; int pix = idx / 12;
    int b = pix >> 14; int hw = pix & 16383; int h = hw >> 7, w = hw & 127;
    int cb = c16*16;
    v2f acc2[8];
    #pragma unroll
    for (int j=0;j<8;j++) acc2[j] = (v2f){bdw[cb+2*j], bdw[cb+2*j+1]};
    #pragma unroll
    for (int dy=-1;dy<=1;dy++){
        int hh=h+dy; if ((unsigned)hh >= (unsigned)Hn) continue;
        #pragma unroll
        for (int dx=-1;dx<=1;dx++){
            int ww=w+dx; if ((unsigned)ww >= (unsigned)Wn) continue;
            const uint4* xp = (const uint4*)(x + ((size_t)((b<<14)+(hh<<7)+ww))*Cn + cb);
            const uint4* wp = (const uint4*)(wdwb + ((dy+1)*3+(dx+1))*Cn + cb);
            #pragma unroll
            for (int cs=0;cs<2;cs++){
                uint4 xu = xp[cs], wu = wp[cs];
                unsigned xa[4] = {xu.x,xu.y,xu.z,xu.w};
                unsigned wa[4] = {wu.x,wu.y,wu.z,wu.w};
                #pragma unroll
                for (int t=0;t<4;t++)
                    acc2[cs*4+t] += up2(xa[t]) * up2(wa[t]);
            }
        }
    }
    bf16 ov[16];
    #pragma unroll
    for (int j=0;j<8;j++){
        float v0 = acc2[j].x, v1 = acc2[j].y;
        ov[2*j]   = __float2bfloat16(v0 / (1.f + __expf(-v0)));
        ov[2*j+1] = __float2bfloat16(v1 / (1.f + __expf(-v1)));
    }
    uint4* op = (uint4*)(out + (size_t)pix*Cn + cb);
    op[0] = ((uint4*)ov)[0];
    op[1] = ((uint4*)ov)[1];
}

// ---------------- deformable sampling, 2 threads per (pix,group), 16 ch each ----------------
// OM row (162 bf16): [0..107] offsets (g*18 + 2k + {h,w}), [108..161] mask logits (g*9+k)
// EXACT round-1 measured version (93.5us): XCD chunk swizzle + 2-tap-ahead register
// pipeline, value-wise bf16 unpack (up2). Round-5 fp16 rewrite spilled to scratch
// (address-taken locals defeated SROA -> 3.2GB scratch writes) - do not reintroduce.

#define LOADTAP(K, S)                                                        \
  { float ph = (float)(h + (K)/3 - 1) + 0.1f*lo16(op[K]);                    \
    float pw = (float)(w + (K)%3 - 1) + 0.1f*hi16(op[K]);                    \
    ph = fminf(fmaxf(ph, 0.f), 127.f);                                       \
    pw = fminf(fmaxf(pw, 0.f), 127.f);                                       \
    int hf = (int)ph, wf = (int)pw;                                          \
    fh##S = ph - (float)hf; fw##S = pw - (float)wf;                          \
    int hc = min(hf+1,127), wc = min(wf+1,127);                              \
    const uint4* p00 = (const uint4*)(xb + ((hf<<7)+wf)*Cn);                 \
    const uint4* p01 = (const uint4*)(xb + ((hf<<7)+wc)*Cn);                 \
    const uint4* p10 = (const uint4*)(xb + ((hc<<7)+wf)*Cn);                 \
    const uint4* p11 = (const uint4*)(xb + ((hc<<7)+wc)*Cn);                 \
    S##00[0]=p00[0]; S##00[1]=p00[1]; S##01[0]=p01[0]; S##01[1]=p01[1];      \
    S##10[0]=p10[0]; S##10[1]=p10[1]; S##11[0]=p11[0]; S##11[1]=p11[1]; }

#define ACCTAP(K, S)                                                         \
  { float a = att[K];                                                        \
    float w00=(1.f-fh##S)*(1.f-fw##S)*a, w01=(1.f-fh##S)*fw##S*a,            \
          w10=fh##S*(1.f-fw##S)*a, w11=fh##S*fw##S*a;                        \
    _Pragma("unroll")                                                        \
    for (int cs=0;cs<2;cs++){                                                \
      unsigned u00[4]={S##00[cs].x,S##00[cs].y,S##00[cs].z,S##00[cs].w};     \
      unsigned u01[4]={S##01[cs].x,S##01[cs].y,S##01[cs].z,S##01[cs].w};     \
      unsigned u10[4]={S##10[cs].x,S##10[cs].y,S##10[cs].z,S##10[cs].w};     \
      unsigned u11[4]={S##11[cs].x,S##11[cs].y,S##11[cs].z,S##11[cs].w};     \
      _Pragma("unroll")                                                      \
      for (int t=0;t<4;t++)                                                  \
        acc2[cs*4+t] += up2(u00[t])*w00 + up2(u01[t])*w01                    \
                      + up2(u10[t])*w10 + up2(u11[t])*w11; } }

__global__ __launch_bounds__(256, 4) void deform_sample(const bf16* __restrict__ P,
        const bf16* __restrict__ OM, bf16* __restrict__ S)
{
    int bid = blockIdx.x;
    int bsw = (bid & 7) * 768 + (bid >> 3);      // bijective, 6144 = 8*768
    int idx = bsw*256 + threadIdx.x;             // NPIX*12 threads
    int half = idx & 1;
    int g = (idx >> 1) % 6;
    int pix = idx / 12;
    int b = pix >> 14; int hw = pix & 16383; int h = hw >> 7, w = hw & 127;
    const bf16* om = OM + (size_t)pix*162;
    const bf16* oml = om + 108 + g*9;
    const unsigned* ofp = (const unsigned*)(om + g*18);

    unsigned op[9];
    #pragma unroll
    for (int k=0;k<9;k++) op[k] = ofp[k];

    float att[9];
    float m = -1e30f;
    #pragma unroll
    for (int k=0;k<9;k++){ att[k] = b2f(oml[k]); m = fmaxf(m, att[k]); }
    float ssum = 0.f;
    #pragma unroll
    for (int k=0;k<9;k++){ att[k] = __expf(att[k]-m); ssum += att[k]; }
    float inv = 1.f/ssum;
    #pragma unroll
    for (int k=0;k<9;k++) att[k] *= inv;

    int chbase = g*GCn + half*16;
    const bf16* xb = P + ((((size_t)b) << 14))*Cn + chbase;

    v2f acc2[8];
    #pragma unroll
    for (int j=0;j<8;j++) acc2[j] = (v2f){0.f, 0.f};

    uint4 A00[2],A01[2],A10[2],A11[2]; float fhA,fwA;
    uint4 B00[2],B01[2],B10[2],B11[2]; float fhB,fwB;

    // 2-ahead pipeline: loads for taps k+1,k+2 in flight while accumulating tap k
    LOADTAP(0, A)
    LOADTAP(1, B)
    ACCTAP(0, A)  LOADTAP(2, A)
    ACCTAP(1, B)  LOADTAP(3, B)
    ACCTAP(2, A)  LOADTAP(4, A)
    ACCTAP(3, B)  LOADTAP(5, B)
    ACCTAP(4, A)  LOADTAP(6, A)
    ACCTAP(5, B)  LOADTAP(7, B)
    ACCTAP(6, A)  LOADTAP(8, A)
    ACCTAP(7, B)
    ACCTAP(8, A)

    bf16 ov[16];
    #pragma unroll
    for (int j=0;j<8;j++){
        ov[2*j]   = __float2bfloat16(acc2[j].x);
        ov[2*j+1] = __float2bfloat16(acc2[j].y);
    }
    uint4* sp = (uint4*)(S + (size_t)pix*Cn + chbase);
    sp[0] = ((uint4*)ov)[0];
    sp[1] = ((uint4*)ov)[1];
}

extern "C" void kernel_launch(void* const* d_in, const int* in_sizes, int n_in,
                              void* d_out, int out_size, void* d_ws, size_t ws_size,
                              hipStream_t stream)
{
    const float* x      = (const float*)d_in[0];
    const float* w_in   = (const float*)d_in[1];
    const float* b_in   = (const float*)d_in[2];
    const float* w_dw   = (const float*)d_in[3];
    const float* b_dw   = (const float*)d_in[4];
    const float* w_pw   = (const float*)d_in[5];
    const float* b_pw   = (const float*)d_in[6];
    const float* w_off  = (const float*)d_in[7];
    const float* b_off  = (const float*)d_in[8];
    const float* w_mask = (const float*)d_in[9];
    const float* b_mask = (const float*)d_in[10];
    const float* w_out  = (const float*)d_in[11];
    const float* b_out  = (const float*)d_in[12];
    float* out = (float*)d_out;

    char* ws = (char*)d_ws;
    size_t off = 0;
    auto carve = [&](size_t bytes)->char* {
        char* p = ws + off; off += (bytes + 255) & ~(size_t)255; return p; };
    bf16* XB  = (bf16*)carve((size_t)NPIX*Cn*2);   // bf16 x
    bf16* P   = (bf16*)carve((size_t)NPIX*Cn*2);   // x_proj
    bf16* D   = (bf16*)carve((size_t)NPIX*Cn*2);   // dw out, later reused as sampled S
    bf16* OM  = (bf16*)carve((size_t)NPIX*162*2);  // offsets|mask logits
    bf16* wfI = (bf16*)carve(36864*2);
    bf16* wfO = (bf16*)carve(36864*2);
    bf16* wfM = (bf16*)carve(36864*2);
    float* bM = (float*)carve(192*4);
    bf16* WDW = (bf16*)carve(1728*2);

    dim3 blk(256);
    cvt_bf16<<<12288, blk, 0, stream>>>(x, XB, (long)NPIX*Cn);
    cvt_bf16<<<1,     blk, 0, stream>>>(w_dw, WDW, 1728);
    swizzle_w<<<144, blk, 0, stream>>>(w_in,  wfI, 192);
    swizzle_w<<<144, blk, 0, stream>>>(w_out, wfO, 192);
    swizzle_omc<<<1158, blk, 0, stream>>>(w_pw, w_off, w_mask, b_pw, b_off, b_mask, wfM, bM);

    gemm6r<bf16><<<1024, blk, 0, stream>>>(XB, (const v8s*)wfI, b_in, P, 192, 192);

    dw_silu<<<6144, blk, 0, stream>>>(XB, WDW, b_dw, D);

    gemm6r<bf16><<<1024, blk, 0, stream>>>(D, (const v8s*)wfM, bM, OM, 162, 162);

    deform_sample<<<6144, blk, 0, stream>>>(P, OM, D);   // S overwrites D

    gemm6r<float><<<1024, blk, 0, stream>>>(D, (const v8s*)wfO, b_out, out, 192, 192);
}